// Round 1
// baseline (103.215 us; speedup 1.0000x reference)
//
#include <hip/hip_runtime.h>

// KroneSoftmax: x[2, 2048, 256] fp32.
// out[b, a*256+k] = softmax_row( x[0][b,a] * x[1][b,k] )
// One block per row. Memory-bound: 512 MB output writes dominate.

constexpr int FA   = 256;
constexpr int FB   = 256;
constexpr int ROWS = 2048;

__global__ __launch_bounds__(256) void krone_softmax_kernel(
    const float* __restrict__ x, float* __restrict__ out) {
  const int row = blockIdx.x;
  const int tid = threadIdx.x;

  const float* __restrict__ xa = x + (size_t)row * FA;
  const float* __restrict__ xb = x + (size_t)ROWS * FA + (size_t)row * FB;

  __shared__ float sa[FA];
  __shared__ float sb[FB];
  __shared__ float wmaxa[4], wmina[4], wmaxb[4], wminb[4];
  __shared__ float wsum[4];

  const float a = xa[tid];
  const float b = xb[tid];
  sa[tid] = a;
  sb[tid] = b;

  // ---- row max of bilinear form via vector extremes (exact) ----
  float maxa = a, mina = a, maxb = b, minb = b;
#pragma unroll
  for (int off = 32; off > 0; off >>= 1) {
    maxa = fmaxf(maxa, __shfl_down(maxa, off));
    mina = fminf(mina, __shfl_down(mina, off));
    maxb = fmaxf(maxb, __shfl_down(maxb, off));
    minb = fminf(minb, __shfl_down(minb, off));
  }
  const int wid = tid >> 6;
  if ((tid & 63) == 0) {
    wmaxa[wid] = maxa; wmina[wid] = mina;
    wmaxb[wid] = maxb; wminb[wid] = minb;
  }
  __syncthreads();
  const float MA = fmaxf(fmaxf(wmaxa[0], wmaxa[1]), fmaxf(wmaxa[2], wmaxa[3]));
  const float mA = fminf(fminf(wmina[0], wmina[1]), fminf(wmina[2], wmina[3]));
  const float MB = fmaxf(fmaxf(wmaxb[0], wmaxb[1]), fmaxf(wmaxb[2], wmaxb[3]));
  const float mB = fminf(fminf(wminb[0], wminb[1]), fminf(wminb[2], wminb[3]));
  const float M = fmaxf(fmaxf(MA * MB, MA * mB), fmaxf(mA * MB, mA * mB));

  // ---- denominator: thread owns column j = tid, loop over a rows ----
  float s = 0.f;
#pragma unroll 8
  for (int i = 0; i < FA; ++i) {
    s += __expf(fmaf(sa[i], b, -M));   // sa[i] is a wave-broadcast LDS read
  }
#pragma unroll
  for (int off = 32; off > 0; off >>= 1) s += __shfl_down(s, off);
  if ((tid & 63) == 0) wsum[wid] = s;
  __syncthreads();
  const float r = 1.0f / (wsum[0] + wsum[1] + wsum[2] + wsum[3]);

  // ---- output: 64 iters x 256 threads x float4, fully coalesced ----
  float* __restrict__ orow = out + (size_t)row * (FA * FB);
  const int ai_base = tid >> 6;            // row-within-quad = wave id
  const int j = (tid & 63) * 4;
  const float4 b4 = *reinterpret_cast<const float4*>(&sb[j]);
#pragma unroll 4
  for (int it = 0; it < 64; ++it) {
    const float av = sa[it * 4 + ai_base]; // wave-uniform broadcast
    float4 v;
    v.x = __expf(fmaf(av, b4.x, -M)) * r;
    v.y = __expf(fmaf(av, b4.y, -M)) * r;
    v.z = __expf(fmaf(av, b4.z, -M)) * r;
    v.w = __expf(fmaf(av, b4.w, -M)) * r;
    *reinterpret_cast<float4*>(&orow[it * 1024 + tid * 4]) = v;
  }
}

extern "C" void kernel_launch(void* const* d_in, const int* in_sizes, int n_in,
                              void* d_out, int out_size, void* d_ws, size_t ws_size,
                              hipStream_t stream) {
  const float* x = (const float*)d_in[0];
  float* out = (float*)d_out;
  krone_softmax_kernel<<<ROWS, 256, 0, stream>>>(x, out);
}